// Round 1
// baseline (61.262 us; speedup 1.0000x reference)
//
#include <hip/hip_runtime.h>
#include <math.h>

#define N_VARS 512
#define DV 4
#define EDGES 2048
#define BATCH 8192
#define CLIP_TANH 10.0f

// ---------------------------------------------------------------------------
// Kernel 1: per-column parameter precompute.
// For each column e of the (masked) weight matrix there are exactly DV-1=3
// nonzeros: rows g in group(e) = {4v..4v+3}, g != e (diagonal masked out).
// We fold the ARM dropout gates z=(u<p), z_tilde=(u>sigmoid(-logit)) into the
// weights, plus the single skip-connection weight per column.
// ---------------------------------------------------------------------------
__global__ __launch_bounds__(256) void precompute_params(
    const float* __restrict__ odd_weights,   // [E,E]
    const float* __restrict__ llr_weights,   // [N,E]
    const float* __restrict__ dropout_logit, // [E]
    const float* __restrict__ u,             // [E,E]
    const float* __restrict__ mask_oe,       // [E,E]
    const float* __restrict__ mask_skip,     // [N,E]
    float4* __restrict__ WZ,                 // [E] (4 masked weights*z)
    float4* __restrict__ WZT,                // [E] (4 masked weights*z_tilde)
    float*  __restrict__ LW)                 // [E]
{
    int e = blockIdx.x * 256 + threadIdx.x;
    if (e >= EDGES) return;
    int v = e >> 2;
    int base = v << 2;

    float logit = dropout_logit[e];
    float p = 1.0f / (1.0f + expf(-logit));   // sigmoid(logit)
    float q = 1.0f / (1.0f + expf(logit));    // sigmoid(-logit)

    float wz[4], wzt[4];
#pragma unroll
    for (int j = 0; j < 4; ++j) {
        size_t off = (size_t)(base + j) * EDGES + e;
        // mask_oe is 0 on the diagonal (g==e), 1 on same-group off-diag
        float w = odd_weights[off] * mask_oe[off];
        float uu = u[off];
        wz[j]  = (uu < p) ? w : 0.0f;
        wzt[j] = (uu > q) ? w : 0.0f;
    }
    WZ[e]  = make_float4(wz[0], wz[1], wz[2], wz[3]);
    WZT[e] = make_float4(wzt[0], wzt[1], wzt[2], wzt[3]);

    size_t soff = (size_t)v * EDGES + e;
    LW[e] = llr_weights[soff] * mask_skip[soff];
}

// ---------------------------------------------------------------------------
// Kernel 2: per-row sum of odd_weights^2 (axis=1, unmasked), combined with
// the p/H1 terms. One block per row, deterministic tree reduction.
// ---------------------------------------------------------------------------
__global__ __launch_bounds__(256) void kl_rows(
    const float* __restrict__ odd_weights,   // [E,E]
    const float* __restrict__ dropout_logit, // [E]
    float* __restrict__ rowv)                // [E]
{
    int e = blockIdx.x;
    int t = threadIdx.x;
    const float* row = odd_weights + (size_t)e * EDGES;
    float s = 0.0f;
#pragma unroll
    for (int i = t; i < EDGES; i += 256) {
        float w = row[i];
        s = fmaf(w, w, s);
    }
#pragma unroll
    for (int off = 32; off > 0; off >>= 1)
        s += __shfl_down(s, off, 64);
    __shared__ float red[4];
    if ((t & 63) == 0) red[t >> 6] = s;
    __syncthreads();
    if (t == 0) {
        float ss = red[0] + red[1] + red[2] + red[3];
        float logit = dropout_logit[e];
        float p = 1.0f / (1.0f + expf(-logit));
        float H1 = -p * logf(p) - (1.0f - p) * logf(1.0f - p);
        rowv[e] = 12.5f * p * ss - H1;   // (KL_SCALE^2/2) = 12.5
    }
}

// Kernel 3: final mean over E row values -> scalar kl_term.
__global__ __launch_bounds__(256) void kl_final(
    const float* __restrict__ rowv, float* __restrict__ out)
{
    int t = threadIdx.x;
    float s = 0.0f;
#pragma unroll
    for (int i = t; i < EDGES; i += 256) s += rowv[i];
#pragma unroll
    for (int off = 32; off > 0; off >>= 1)
        s += __shfl_down(s, off, 64);
    __shared__ float red[4];
    if ((t & 63) == 0) red[t >> 6] = s;
    __syncthreads();
    if (t == 0) out[0] = (red[0] + red[1] + red[2] + red[3]) / (float)EDGES;
}

// tanh(m/2) = (e^m - 1) / (e^m + 1), m clipped to [-10,10]
__device__ __forceinline__ float tanh_half(float m) {
    float t = __expf(m);
    return (t - 1.0f) / (t + 1.0f);
}

// ---------------------------------------------------------------------------
// Kernel 4: main elementwise pass. One thread per (row b, variable group v):
// float4 x load, 4 output columns, two 4-wide FMA dots each, float4 stores.
// ---------------------------------------------------------------------------
__global__ __launch_bounds__(256) void main_kernel(
    const float* __restrict__ x,    // [B,E]
    const float* __restrict__ llr,  // [B,N]
    const float4* __restrict__ WZ,
    const float4* __restrict__ WZT,
    const float*  __restrict__ LW,
    float* __restrict__ out0,       // [B,E]
    float* __restrict__ out1)       // [B,E]
{
    int idx = blockIdx.x * 256 + threadIdx.x;   // B*N_VARS threads
    int b = idx >> 9;          // /512
    int v = idx & 511;

    float4 x4 = ((const float4*)(x + (size_t)b * EDGES))[v];
    float l = llr[(size_t)b * N_VARS + v];

    float o0[4], o1[4];
#pragma unroll
    for (int c = 0; c < 4; ++c) {
        int e = (v << 2) + c;
        float4 wz  = WZ[e];
        float4 wzt = WZT[e];
        float lt = l * LW[e];
        float m  = fmaf(x4.x, wz.x,  fmaf(x4.y, wz.y,  fmaf(x4.z, wz.z,  fmaf(x4.w, wz.w,  lt))));
        float mt = fmaf(x4.x, wzt.x, fmaf(x4.y, wzt.y, fmaf(x4.z, wzt.z, fmaf(x4.w, wzt.w, lt))));
        m  = fminf(fmaxf(m,  -CLIP_TANH), CLIP_TANH);
        mt = fminf(fmaxf(mt, -CLIP_TANH), CLIP_TANH);
        o0[c] = tanh_half(m);
        o1[c] = tanh_half(mt);
    }
    ((float4*)(out0 + (size_t)b * EDGES))[v] = make_float4(o0[0], o0[1], o0[2], o0[3]);
    ((float4*)(out1 + (size_t)b * EDGES))[v] = make_float4(o1[0], o1[1], o1[2], o1[3]);
}

extern "C" void kernel_launch(void* const* d_in, const int* in_sizes, int n_in,
                              void* d_out, int out_size, void* d_ws, size_t ws_size,
                              hipStream_t stream) {
    const float* x             = (const float*)d_in[0];
    const float* llr           = (const float*)d_in[1];
    const float* odd_weights   = (const float*)d_in[2];
    const float* llr_weights   = (const float*)d_in[3];
    const float* dropout_logit = (const float*)d_in[4];
    const float* u             = (const float*)d_in[5];
    const float* mask_oe       = (const float*)d_in[6];
    const float* mask_skip     = (const float*)d_in[7];

    float* out0 = (float*)d_out;
    float* out1 = out0 + (size_t)BATCH * EDGES;
    float* kl   = out0 + (size_t)2 * BATCH * EDGES;

    char* ws = (char*)d_ws;
    float4* WZ  = (float4*)(ws);              // 32 KiB
    float4* WZT = (float4*)(ws + 32768);      // 32 KiB
    float*  LW  = (float*) (ws + 65536);      // 8 KiB
    float*  ROWV= (float*) (ws + 73728);      // 8 KiB

    precompute_params<<<EDGES / 256, 256, 0, stream>>>(
        odd_weights, llr_weights, dropout_logit, u, mask_oe, mask_skip, WZ, WZT, LW);
    kl_rows<<<EDGES, 256, 0, stream>>>(odd_weights, dropout_logit, ROWV);
    kl_final<<<1, 256, 0, stream>>>(ROWV, kl);
    main_kernel<<<(BATCH * N_VARS) / 256, 256, 0, stream>>>(
        x, llr, WZ, WZT, LW, out0, out1);
}

// Round 5
// 53.504 us; speedup vs baseline: 1.1450x; 1.1450x over previous
//
#include <hip/hip_runtime.h>
#include <math.h>

#define N_VARS 512
#define DV 4
#define EDGES 2048
#define BATCH 8192
#define CLIP_TANH 10.0f
#define ROWS 8   // batch rows per thread in main kernel

// ---------------------------------------------------------------------------
// Kernel 1: per-column parameter precompute (tiny).
// Each column e of the masked weight matrix has nonzeros only at rows
// g in group(e) = {4v..4v+3}; diagonal is masked. Fold ARM gates into weights.
// ---------------------------------------------------------------------------
__global__ __launch_bounds__(256) void precompute_params(
    const float* __restrict__ odd_weights,   // [E,E]
    const float* __restrict__ llr_weights,   // [N,E]
    const float* __restrict__ dropout_logit, // [E]
    const float* __restrict__ u,             // [E,E]
    const float* __restrict__ mask_oe,       // [E,E]
    const float* __restrict__ mask_skip,     // [N,E]
    float4* __restrict__ WZ,                 // [E]
    float4* __restrict__ WZT,                // [E]
    float*  __restrict__ LW)                 // [E]
{
    int e = blockIdx.x * 256 + threadIdx.x;
    if (e >= EDGES) return;
    int v = e >> 2;
    int base = v << 2;

    float logit = dropout_logit[e];
    float p = 1.0f / (1.0f + expf(-logit));   // sigmoid(logit)
    float q = 1.0f / (1.0f + expf(logit));    // sigmoid(-logit)

    float wz[4], wzt[4];
#pragma unroll
    for (int j = 0; j < 4; ++j) {
        size_t off = (size_t)(base + j) * EDGES + e;
        float w = odd_weights[off] * mask_oe[off];
        float uu = u[off];
        wz[j]  = (uu < p) ? w : 0.0f;
        wzt[j] = (uu > q) ? w : 0.0f;
    }
    WZ[e]  = make_float4(wz[0], wz[1], wz[2], wz[3]);
    WZT[e] = make_float4(wzt[0], wzt[1], wzt[2], wzt[3]);

    size_t soff = (size_t)v * EDGES + e;
    LW[e] = llr_weights[soff] * mask_skip[soff];
}

// ---------------------------------------------------------------------------
// Kernel 2: per-row sum of odd_weights^2 (axis=1, unmasked) + p/H1 terms.
// ---------------------------------------------------------------------------
__global__ __launch_bounds__(256) void kl_rows(
    const float* __restrict__ odd_weights,   // [E,E]
    const float* __restrict__ dropout_logit, // [E]
    float* __restrict__ rowv)                // [E]
{
    int e = blockIdx.x;
    int t = threadIdx.x;
    const float4* row = (const float4*)(odd_weights + (size_t)e * EDGES);
    float s = 0.0f;
#pragma unroll
    for (int i = t; i < EDGES / 4; i += 256) {
        float4 w = row[i];
        s = fmaf(w.x, w.x, s);
        s = fmaf(w.y, w.y, s);
        s = fmaf(w.z, w.z, s);
        s = fmaf(w.w, w.w, s);
    }
#pragma unroll
    for (int off = 32; off > 0; off >>= 1)
        s += __shfl_down(s, off, 64);
    __shared__ float red[4];
    if ((t & 63) == 0) red[t >> 6] = s;
    __syncthreads();
    if (t == 0) {
        float ss = red[0] + red[1] + red[2] + red[3];
        float logit = dropout_logit[e];
        float p = 1.0f / (1.0f + expf(-logit));
        float H1 = -p * logf(p) - (1.0f - p) * logf(1.0f - p);
        rowv[e] = 12.5f * p * ss - H1;   // (KL_SCALE^2/2) = 12.5
    }
}

// Kernel 3: final mean over E row values -> scalar kl_term.
__global__ __launch_bounds__(256) void kl_final(
    const float* __restrict__ rowv, float* __restrict__ out)
{
    int t = threadIdx.x;
    float s = 0.0f;
#pragma unroll
    for (int i = t; i < EDGES; i += 256) s += rowv[i];
#pragma unroll
    for (int off = 32; off > 0; off >>= 1)
        s += __shfl_down(s, off, 64);
    __shared__ float red[4];
    if ((t & 63) == 0) red[t >> 6] = s;
    __syncthreads();
    if (t == 0) out[0] = (red[0] + red[1] + red[2] + red[3]) / (float)EDGES;
}

// tanh(m/2) = (e^m - 1) / (e^m + 1), m clipped to [-10,10]
__device__ __forceinline__ float tanh_half(float m) {
    float t = __expf(m);
    return (t - 1.0f) / (t + 1.0f);
}

// ---------------------------------------------------------------------------
// Kernel 4: main pass. One thread per (variable group v, chunk of ROWS rows).
// Params (36 floats) are loaded ONCE into registers and reused across ROWS
// batch rows; the fully unrolled row loop issues ROWS independent x-loads
// for latency hiding. Consecutive threads share a chunk and have consecutive
// v -> all global accesses coalesced (float4).
// ---------------------------------------------------------------------------
__global__ __launch_bounds__(256) void main_kernel(
    const float* __restrict__ x,    // [B,E]
    const float* __restrict__ llr,  // [B,N]
    const float4* __restrict__ WZ,
    const float4* __restrict__ WZT,
    const float*  __restrict__ LW,
    float* __restrict__ out0,       // [B,E]
    float* __restrict__ out1)       // [B,E]
{
    int idx = blockIdx.x * 256 + threadIdx.x;   // (B/ROWS)*N_VARS threads
    int v = idx & (N_VARS - 1);
    int b0 = (idx >> 9) * ROWS;

    // register-resident params for this variable group's 4 output columns
    float4 wz[4], wzt[4];
    float lw[4];
#pragma unroll
    for (int c = 0; c < 4; ++c) {
        int e = (v << 2) + c;
        wz[c]  = WZ[e];
        wzt[c] = WZT[e];
        lw[c]  = LW[e];
    }

    // issue all x / llr loads up front (independent -> overlapped)
    float4 x4[ROWS];
    float  l[ROWS];
#pragma unroll
    for (int r = 0; r < ROWS; ++r) {
        x4[r] = ((const float4*)(x + (size_t)(b0 + r) * EDGES))[v];
        l[r]  = llr[(size_t)(b0 + r) * N_VARS + v];
    }

#pragma unroll
    for (int r = 0; r < ROWS; ++r) {
        float o0[4], o1[4];
#pragma unroll
        for (int c = 0; c < 4; ++c) {
            float lt = l[r] * lw[c];
            float m  = fmaf(x4[r].x, wz[c].x,  fmaf(x4[r].y, wz[c].y,
                       fmaf(x4[r].z, wz[c].z,  fmaf(x4[r].w, wz[c].w,  lt))));
            float mt = fmaf(x4[r].x, wzt[c].x, fmaf(x4[r].y, wzt[c].y,
                       fmaf(x4[r].z, wzt[c].z, fmaf(x4[r].w, wzt[c].w, lt))));
            m  = fminf(fmaxf(m,  -CLIP_TANH), CLIP_TANH);
            mt = fminf(fmaxf(mt, -CLIP_TANH), CLIP_TANH);
            o0[c] = tanh_half(m);
            o1[c] = tanh_half(mt);
        }
        ((float4*)(out0 + (size_t)(b0 + r) * EDGES))[v] =
            make_float4(o0[0], o0[1], o0[2], o0[3]);
        ((float4*)(out1 + (size_t)(b0 + r) * EDGES))[v] =
            make_float4(o1[0], o1[1], o1[2], o1[3]);
    }
}

extern "C" void kernel_launch(void* const* d_in, const int* in_sizes, int n_in,
                              void* d_out, int out_size, void* d_ws, size_t ws_size,
                              hipStream_t stream) {
    const float* x             = (const float*)d_in[0];
    const float* llr           = (const float*)d_in[1];
    const float* odd_weights   = (const float*)d_in[2];
    const float* llr_weights   = (const float*)d_in[3];
    const float* dropout_logit = (const float*)d_in[4];
    const float* u             = (const float*)d_in[5];
    const float* mask_oe       = (const float*)d_in[6];
    const float* mask_skip     = (const float*)d_in[7];

    float* out0 = (float*)d_out;
    float* out1 = out0 + (size_t)BATCH * EDGES;
    float* kl   = out0 + (size_t)2 * BATCH * EDGES;

    char* ws = (char*)d_ws;
    float4* WZ  = (float4*)(ws);              // 32 KiB
    float4* WZT = (float4*)(ws + 32768);      // 32 KiB
    float*  LW  = (float*) (ws + 65536);      // 8 KiB
    float*  ROWV= (float*) (ws + 73728);      // 8 KiB

    precompute_params<<<EDGES / 256, 256, 0, stream>>>(
        odd_weights, llr_weights, dropout_logit, u, mask_oe, mask_skip, WZ, WZT, LW);
    kl_rows<<<EDGES, 256, 0, stream>>>(odd_weights, dropout_logit, ROWV);
    kl_final<<<1, 256, 0, stream>>>(ROWV, kl);

    int threads = (BATCH / ROWS) * N_VARS;    // 524288
    main_kernel<<<threads / 256, 256, 0, stream>>>(
        x, llr, WZ, WZT, LW, out0, out1);
}